// Round 1
// baseline (1021.488 us; speedup 1.0000x reference)
//
#include <hip/hip_runtime.h>

typedef unsigned short u16;
typedef __bf16 bf16x8 __attribute__((ext_vector_type(8)));
typedef float  f32x4  __attribute__((ext_vector_type(4)));

__device__ __forceinline__ float b2f(u16 u) {
    unsigned int v = ((unsigned int)u) << 16;
    return __builtin_bit_cast(float, v);
}
__device__ __forceinline__ u16 f2b(float f) {
    unsigned int v = __builtin_bit_cast(unsigned int, f);
    v += 0x7fffu + ((v >> 16) & 1u);
    return (u16)(v >> 16);
}

// async global->LDS, 16B per lane; LDS dest = wave-uniform base + lane*16
#define GLD16(gp, lp) __builtin_amdgcn_global_load_lds( \
    (const __attribute__((address_space(1))) void*)(gp), \
    (__attribute__((address_space(3))) void*)(lp), 16, 0, 0)

// ---------------------------------------------------------------- prep kernels

__global__ __launch_bounds__(256) void convert_x(const float* __restrict__ x,
                                                 u16* __restrict__ xb) {
    size_t i = ((size_t)blockIdx.x * 256 + threadIdx.x) * 8;
    float4 v0 = *(const float4*)(x + i);
    float4 v1 = *(const float4*)(x + i + 4);
    ushort4 o0, o1;
    o0.x = f2b(v0.x); o0.y = f2b(v0.y); o0.z = f2b(v0.z); o0.w = f2b(v0.w);
    o1.x = f2b(v1.x); o1.y = f2b(v1.y); o1.z = f2b(v1.z); o1.w = f2b(v1.w);
    *(ushort4*)(xb + i)     = o0;
    *(ushort4*)(xb + i + 4) = o1;
}

// Wt[n][k] = bf16(W[k][n]), 1024x1024, LDS-tiled transpose
__global__ __launch_bounds__(256) void transpose_w(const float* __restrict__ W,
                                                   u16* __restrict__ Wt) {
    __shared__ float tile[64][65];
    int kt = (blockIdx.x & 15) * 64;
    int nt = (blockIdx.x >> 4) * 64;
    int tid = threadIdx.x;
    int r = tid >> 4, c4 = (tid & 15) * 4;
    #pragma unroll
    for (int p = 0; p < 4; ++p) {
        int k = kt + p * 16 + r;
        float4 v = *(const float4*)(W + (size_t)k * 1024 + nt + c4);
        tile[c4 + 0][p * 16 + r] = v.x;
        tile[c4 + 1][p * 16 + r] = v.y;
        tile[c4 + 2][p * 16 + r] = v.z;
        tile[c4 + 3][p * 16 + r] = v.w;
    }
    __syncthreads();
    #pragma unroll
    for (int p = 0; p < 4; ++p) {
        int nl = p * 16 + r;
        ushort4 o;
        o.x = f2b(tile[nl][c4 + 0]); o.y = f2b(tile[nl][c4 + 1]);
        o.z = f2b(tile[nl][c4 + 2]); o.w = f2b(tile[nl][c4 + 3]);
        *(ushort4*)(Wt + (size_t)(nt + nl) * 1024 + kt + c4) = o;
    }
}

// Wut[b][n][k] = bf16(Wu[k][n] * p_av[b][k])  (fold p_av into per-batch B)
__global__ __launch_bounds__(256) void wu_prime(const float* __restrict__ Wu,
                                                const float* __restrict__ p_av,
                                                u16* __restrict__ Wut) {
    __shared__ float tile[64][65];
    int kt = (blockIdx.x & 15) * 64;
    int nt = (blockIdx.x >> 4) * 64;
    int tid = threadIdx.x;
    int r = tid >> 4, c4 = (tid & 15) * 4;
    #pragma unroll
    for (int p = 0; p < 4; ++p) {
        int k = kt + p * 16 + r;
        float4 v = *(const float4*)(Wu + (size_t)k * 1024 + nt + c4);
        tile[c4 + 0][p * 16 + r] = v.x;
        tile[c4 + 1][p * 16 + r] = v.y;
        tile[c4 + 2][p * 16 + r] = v.z;
        tile[c4 + 3][p * 16 + r] = v.w;
    }
    __syncthreads();
    for (int b = 0; b < 8; ++b) {
        float4 pv = *(const float4*)(p_av + (size_t)b * 1024 + kt + c4);
        #pragma unroll
        for (int p = 0; p < 4; ++p) {
            int nl = p * 16 + r;
            ushort4 o;
            o.x = f2b(tile[nl][c4 + 0] * pv.x);
            o.y = f2b(tile[nl][c4 + 1] * pv.y);
            o.z = f2b(tile[nl][c4 + 2] * pv.z);
            o.w = f2b(tile[nl][c4 + 3] * pv.w);
            *(ushort4*)(Wut + ((size_t)b * 1024 + nt + nl) * 1024 + kt + c4) = o;
        }
    }
}

__global__ __launch_bounds__(256) void wat_prep(const float* __restrict__ Wa,
                                                u16* __restrict__ Wat) {
    int idx = blockIdx.x * 256 + threadIdx.x;   // 16384 = 16 h * 1024 k
    int h = idx >> 10, k = idx & 1023;
    Wat[idx] = f2b(Wa[(k << 4) + h]);
}

// Wbt[b][h][k] = bf16(Wb[k][h] * q_av[b][k])
__global__ __launch_bounds__(256) void wbt_prep(const float* __restrict__ Wb,
                                                const float* __restrict__ q_av,
                                                u16* __restrict__ Wbt) {
    int idx = blockIdx.x * 256 + threadIdx.x;   // 131072
    int b = idx >> 14, rem = idx & 16383;
    int h = rem >> 10, k = rem & 1023;
    Wbt[idx] = f2b(Wb[(k << 4) + h] * q_av[(b << 10) + k]);
}

__global__ __launch_bounds__(256) void bias_concat(const float* __restrict__ bq,
                                                   const float* __restrict__ bk,
                                                   const float* __restrict__ bv,
                                                   float* __restrict__ outb) {
    int i = blockIdx.x * 256 + threadIdx.x;     // 3072
    outb[i] = (i < 1024) ? bq[i] : (i < 2048 ? bk[i - 1024] : bv[i - 2048]);
}

// ---------------------------------------------------------------- main GEMM
// m97 structure: 128x128 tile, BK=32, 4 waves each 64x64 (4x4 of 16x16x32 MFMA),
// global_load_lds width=16 staging, 2-barrier K-loop.
__global__ __launch_bounds__(256)
void gemm_bf16(const u16* __restrict__ A, int lda,
               const u16* __restrict__ Bt,        // [N][K] bf16 (B^T)
               const float* __restrict__ bias,    // [N]
               const u16* __restrict__ addsrc, int ldadd,  // optional epilogue add
               u16* __restrict__ C, int ldc,
               int N, int K, int batch_rows) {    // batch_rows>0: Bt per-batch
    __shared__ u16 As[128 * 32];
    __shared__ u16 Bs[128 * 32];
    int ntiles = N >> 7;
    int tm = blockIdx.x / ntiles, tn = blockIdx.x % ntiles;
    int m0 = tm << 7, n0 = tn << 7;
    if (batch_rows > 0) Bt += (size_t)(m0 / batch_rows) * N * K;
    int tid = threadIdx.x, lane = tid & 63, w = tid >> 6;
    int wm = (w >> 1) << 6, wn = (w & 1) << 6;
    int srow = lane >> 2, scol = (lane & 3) << 3;
    int quad = lane >> 4, l16 = lane & 15;
    f32x4 zero = {0.f, 0.f, 0.f, 0.f};
    f32x4 acc[4][4];
    #pragma unroll
    for (int i = 0; i < 4; ++i)
        #pragma unroll
        for (int j = 0; j < 4; ++j) acc[i][j] = zero;

    for (int kt = 0; kt < K; kt += 32) {
        __syncthreads();
        #pragma unroll
        for (int rr = 0; rr < 2; ++rr) {
            int ch = (w << 1) + rr;          // 0..7, 16 rows per chunk
            int row = (ch << 4) + srow;
            const u16* ga = A  + (size_t)(m0 + row) * lda + kt + scol;
            GLD16(ga, &As[ch << 9]);
            const u16* gb = Bt + (size_t)(n0 + row) * K   + kt + scol;
            GLD16(gb, &Bs[ch << 9]);
        }
        __syncthreads();
        bf16x8 a[4], b[4];
        #pragma unroll
        for (int i = 0; i < 4; ++i)
            a[i] = *(const bf16x8*)&As[((wm + (i << 4) + l16) << 5) + (quad << 3)];
        #pragma unroll
        for (int i = 0; i < 4; ++i)
            b[i] = *(const bf16x8*)&Bs[((wn + (i << 4) + l16) << 5) + (quad << 3)];
        #pragma unroll
        for (int mi = 0; mi < 4; ++mi)
            #pragma unroll
            for (int ni = 0; ni < 4; ++ni)
                acc[mi][ni] = __builtin_amdgcn_mfma_f32_16x16x32_bf16(
                    a[mi], b[ni], acc[mi][ni], 0, 0, 0);
    }
    // epilogue: C/D layout col=lane&15, row=quad*4+reg (verified m89/m91)
    #pragma unroll
    for (int mi = 0; mi < 4; ++mi) {
        #pragma unroll
        for (int ni = 0; ni < 4; ++ni) {
            int col = n0 + wn + (ni << 4) + l16;
            float bv = bias[col];
            #pragma unroll
            for (int rg = 0; rg < 4; ++rg) {
                int rowg = m0 + wm + (mi << 4) + (quad << 2) + rg;
                float vv = acc[mi][ni][rg] + bv;
                if (addsrc) vv += b2f(addsrc[(size_t)rowg * ldadd + col]);
                C[(size_t)rowg * ldc + col] = f2b(vv);
            }
        }
    }
}

// ------------------------------------------------- score GEMM ([Nrows]x[16])
// out[b][h][s] = 0.125*(dot(A_row, Bt[h]) + bias16[h]) + mask[b][s]
__global__ __launch_bounds__(256)
void score_gemm(const u16* __restrict__ A, int lda,
                const u16* __restrict__ Bt,     // [16][1024] bf16 (per batch if batched)
                const float* __restrict__ bias16,
                const float* __restrict__ mask, // [8][4096]
                float* __restrict__ outsc,      // [8][16][4096]
                int batched) {
    __shared__ u16 As[64 * 32];
    int m0 = blockIdx.x << 6;
    int tid = threadIdx.x, lane = tid & 63, w = tid >> 6;
    int srow = lane >> 2, scol = (lane & 3) << 3;
    int quad = lane >> 4, l16 = lane & 15;
    const u16* Bb = Bt + (batched ? ((size_t)(m0 >> 12) << 14) : 0);
    f32x4 acc = {0.f, 0.f, 0.f, 0.f};
    for (int kt = 0; kt < 1024; kt += 32) {
        __syncthreads();
        const u16* ga = A + (size_t)(m0 + (w << 4) + srow) * lda + kt + scol;
        GLD16(ga, &As[w << 9]);
        __syncthreads();
        bf16x8 a = *(const bf16x8*)&As[(((w << 4) + l16) << 5) + (quad << 3)];
        bf16x8 b = *(const bf16x8*)&Bb[((size_t)l16 << 10) + kt + (quad << 3)];
        acc = __builtin_amdgcn_mfma_f32_16x16x32_bf16(a, b, acc, 0, 0, 0);
    }
    int bidx = m0 >> 12;
    int sbase = (m0 & 4095) + (w << 4) + (quad << 2);
    float bv = bias16[l16];
    float* orow = outsc + (((size_t)bidx << 4) + l16) * 4096;
    const float* mrow = mask + ((size_t)bidx << 12);
    #pragma unroll
    for (int rg = 0; rg < 4; ++rg)
        orow[sbase + rg] = 0.125f * (acc[rg] + bv) + mrow[sbase + rg];
}

// ------------------------------------- softmax over S + weighted pool per (b,h)
__global__ __launch_bounds__(256)
void pool_kernel(const float* __restrict__ score,   // [8][16][4096]
                 const u16* __restrict__ X, int ldx, // q or k rows, bf16
                 const float* __restrict__ mulvec,   // null or q_av [8][1024]
                 float* __restrict__ outav) {        // [8][1024]
    __shared__ float wbuf[4096];
    __shared__ float red[4];
    __shared__ float psum[16][64];
    int b = blockIdx.x >> 4, h = blockIdx.x & 15;
    int tid = threadIdx.x, lane = tid & 63, w = tid >> 6;
    const float* srow = score + (((size_t)b << 4) + h) * 4096;
    float mx = -1e30f;
    for (int s = tid; s < 4096; s += 256) mx = fmaxf(mx, srow[s]);
    for (int o = 32; o; o >>= 1) mx = fmaxf(mx, __shfl_xor(mx, o));
    if (lane == 0) red[w] = mx;
    __syncthreads();
    mx = fmaxf(fmaxf(red[0], red[1]), fmaxf(red[2], red[3]));
    __syncthreads();
    float sm = 0.f;
    for (int s = tid; s < 4096; s += 256) {
        float e = __expf(srow[s] - mx);
        wbuf[s] = e;
        sm += e;
    }
    for (int o = 32; o; o >>= 1) sm += __shfl_xor(sm, o);
    if (lane == 0) red[w] = sm;
    __syncthreads();
    float inv = 1.f / (red[0] + red[1] + red[2] + red[3]);
    int dg = (tid & 15) << 2;   // 4 of 64 dims in head
    int sc = tid >> 4;          // 16 s-chunks of 256
    const u16* base = X + ((size_t)(b << 12)) * ldx + (h << 6) + dg;
    float a0 = 0, a1 = 0, a2 = 0, a3 = 0;
    for (int s = sc << 8; s < (sc << 8) + 256; ++s) {
        float wv = wbuf[s];
        ushort4 uv = *(const ushort4*)(base + (size_t)s * ldx);
        a0 += wv * b2f(uv.x); a1 += wv * b2f(uv.y);
        a2 += wv * b2f(uv.z); a3 += wv * b2f(uv.w);
    }
    psum[sc][dg + 0] = a0; psum[sc][dg + 1] = a1;
    psum[sc][dg + 2] = a2; psum[sc][dg + 3] = a3;
    __syncthreads();
    if (tid < 64) {
        float t = 0.f;
        #pragma unroll
        for (int j = 0; j < 16; ++j) t += psum[j][tid];
        t *= inv;
        if (mulvec) t *= mulvec[((size_t)b << 10) + (h << 6) + tid];
        outav[((size_t)b << 10) + (h << 6) + tid] = t;
    }
}

// ---------------------------------------------------------------- layernorm
__global__ __launch_bounds__(256)
void ln_kernel(const u16* __restrict__ Z, const float* __restrict__ g,
               const float* __restrict__ bta, float* __restrict__ outp) {
    __shared__ float rs1[4], rs2[4];
    int row = blockIdx.x, tid = threadIdx.x;
    const u16* zr = Z + ((size_t)row << 10);
    ushort4 uv = *(const ushort4*)(zr + (tid << 2));
    float v0 = b2f(uv.x), v1 = b2f(uv.y), v2 = b2f(uv.z), v3 = b2f(uv.w);
    float s = v0 + v1 + v2 + v3;
    float s2 = v0 * v0 + v1 * v1 + v2 * v2 + v3 * v3;
    for (int o = 32; o; o >>= 1) { s += __shfl_xor(s, o); s2 += __shfl_xor(s2, o); }
    if ((tid & 63) == 0) { rs1[tid >> 6] = s; rs2[tid >> 6] = s2; }
    __syncthreads();
    float S = rs1[0] + rs1[1] + rs1[2] + rs1[3];
    float S2 = rs2[0] + rs2[1] + rs2[2] + rs2[3];
    float mean = S * (1.0f / 1024.0f);
    float var = S2 * (1.0f / 1024.0f) - mean * mean;
    float inv = rsqrtf(var + 1e-6f);
    int c = tid << 2;
    float4 o4;
    o4.x = (v0 - mean) * inv * g[c + 0] + bta[c + 0];
    o4.y = (v1 - mean) * inv * g[c + 1] + bta[c + 1];
    o4.z = (v2 - mean) * inv * g[c + 2] + bta[c + 2];
    o4.w = (v3 - mean) * inv * g[c + 3] + bta[c + 3];
    *(float4*)(outp + ((size_t)row << 10) + c) = o4;
}

// ---------------------------------------------------------------- launch

extern "C" void kernel_launch(void* const* d_in, const int* in_sizes, int n_in,
                              void* d_out, int out_size, void* d_ws, size_t ws_size,
                              hipStream_t stream) {
    (void)in_sizes; (void)n_in; (void)out_size;
    const float* x    = (const float*)d_in[0];
    const float* mask = (const float*)d_in[1];
    const float* Wq   = (const float*)d_in[2];
    const float* bq   = (const float*)d_in[3];
    const float* Wk   = (const float*)d_in[4];
    const float* bk   = (const float*)d_in[5];
    const float* Wv   = (const float*)d_in[6];
    const float* bv   = (const float*)d_in[7];
    const float* Wa   = (const float*)d_in[8];
    const float* ba   = (const float*)d_in[9];
    const float* Wb   = (const float*)d_in[10];
    const float* bb   = (const float*)d_in[11];
    const float* Wu   = (const float*)d_in[12];
    const float* bu   = (const float*)d_in[13];
    const float* Wo   = (const float*)d_in[14];
    const float* bo   = (const float*)d_in[15];
    const float* ln_g = (const float*)d_in[16];
    const float* ln_b = (const float*)d_in[17];
    float* outp = (float*)d_out;

    char* ws = (char*)d_ws;
    // layout (bytes, all 256-aligned)
    u16*   xb    = (u16*)(ws);                     //  67,108,864  x bf16; later aliased by z
    u16*   qkv   = (u16*)(ws + 67108864);          // 201,326,592  [32768][3072]; q-region aliased by t
    u16*   Wqkvt = (u16*)(ws + 268435456);         //   6,291,456
    u16*   Wot   = (u16*)(ws + 274726912);         //   2,097,152
    u16*   Wat   = (u16*)(ws + 276824064);         //      32,768
    u16*   Wbt   = (u16*)(ws + 276856832);         //     262,144
    float* score = (float*)(ws + 277118976);       //   2,097,152 (reused for a & b scores)
    float* q_av  = (float*)(ws + 279216128);       //      32,768
    float* p_av  = (float*)(ws + 279248896);       //      32,768
    float* biasq = (float*)(ws + 279281664);       //      12,288
    u16*   Wubt  = (u16*)(ws + 279293952);         //  16,777,216  -> total 296,071,168
    if (ws_size < 296071168ULL) return;

    convert_x<<<16384, 256, 0, stream>>>(x, xb);
    transpose_w<<<256, 256, 0, stream>>>(Wq, Wqkvt);
    transpose_w<<<256, 256, 0, stream>>>(Wk, Wqkvt + 1048576);
    transpose_w<<<256, 256, 0, stream>>>(Wv, Wqkvt + 2097152);
    transpose_w<<<256, 256, 0, stream>>>(Wo, Wot);
    wat_prep<<<64, 256, 0, stream>>>(Wa, Wat);
    bias_concat<<<12, 256, 0, stream>>>(bq, bk, bv, biasq);

    // qkv = x @ [Wq|Wk|Wv] + bias   (M=32768, N=3072, K=1024)
    gemm_bf16<<<6144, 256, 0, stream>>>(xb, 1024, Wqkvt, biasq,
                                        nullptr, 0, qkv, 3072, 3072, 1024, 0);
    // ascore
    score_gemm<<<512, 256, 0, stream>>>(qkv, 3072, Wat, ba, mask, score, 0);
    // alpha softmax+pool -> q_av
    pool_kernel<<<128, 256, 0, stream>>>(score, qkv, 3072, nullptr, q_av);
    // per-batch Wb' = diag(q_av) Wb
    wbt_prep<<<512, 256, 0, stream>>>(Wb, q_av, Wbt);
    // bscore = k @ Wb'
    score_gemm<<<512, 256, 0, stream>>>(qkv + 1024, 3072, Wbt, bb, mask, score, 1);
    // beta softmax+pool, times q_av -> p_av
    pool_kernel<<<128, 256, 0, stream>>>(score, qkv + 1024, 3072, q_av, p_av);
    // per-batch Wu' = diag(p_av) Wu (transposed, bf16)
    wu_prime<<<256, 256, 0, stream>>>(Wu, p_av, Wubt);
    // t = v @ Wu'_b + bu + q   (writes over q region; element read-before-write)
    gemm_bf16<<<2048, 256, 0, stream>>>(qkv + 2048, 3072, Wubt, bu,
                                        qkv, 3072, qkv, 3072, 1024, 1024, 4096);
    // z = t @ Wo^T + bo + x    (writes over xb; element read-before-write)
    gemm_bf16<<<2048, 256, 0, stream>>>(qkv, 3072, Wot, bo,
                                        xb, 1024, xb, 1024, 1024, 1024, 0);
    // layernorm -> out (f32)
    ln_kernel<<<32768, 256, 0, stream>>>(xb, ln_g, ln_b, outp);
}

// Round 2
// 935.775 us; speedup vs baseline: 1.0916x; 1.0916x over previous
//
#include <hip/hip_runtime.h>

typedef unsigned short u16;
typedef __bf16 bf16x8 __attribute__((ext_vector_type(8)));
typedef float  f32x4  __attribute__((ext_vector_type(4)));

__device__ __forceinline__ float b2f(u16 u) {
    unsigned int v = ((unsigned int)u) << 16;
    return __builtin_bit_cast(float, v);
}
__device__ __forceinline__ u16 f2b(float f) {
    unsigned int v = __builtin_bit_cast(unsigned int, f);
    v += 0x7fffu + ((v >> 16) & 1u);
    return (u16)(v >> 16);
}

// async global->LDS, 16B per lane; LDS dest = wave-uniform base + lane*16
#define GLD16(gp, lp) __builtin_amdgcn_global_load_lds( \
    (const __attribute__((address_space(1))) void*)(gp), \
    (__attribute__((address_space(3))) void*)(lp), 16, 0, 0)

// ---------------------------------------------------------------- prep kernels

__global__ __launch_bounds__(256) void convert_x(const float* __restrict__ x,
                                                 u16* __restrict__ xb) {
    size_t i = ((size_t)blockIdx.x * 256 + threadIdx.x) * 8;
    float4 v0 = *(const float4*)(x + i);
    float4 v1 = *(const float4*)(x + i + 4);
    ushort4 o0, o1;
    o0.x = f2b(v0.x); o0.y = f2b(v0.y); o0.z = f2b(v0.z); o0.w = f2b(v0.w);
    o1.x = f2b(v1.x); o1.y = f2b(v1.y); o1.z = f2b(v1.z); o1.w = f2b(v1.w);
    *(ushort4*)(xb + i)     = o0;
    *(ushort4*)(xb + i + 4) = o1;
}

// Wt[n][k] = bf16(W[k][n]), 1024x1024, LDS-tiled transpose
__global__ __launch_bounds__(256) void transpose_w(const float* __restrict__ W,
                                                   u16* __restrict__ Wt) {
    __shared__ float tile[64][65];
    int kt = (blockIdx.x & 15) * 64;
    int nt = (blockIdx.x >> 4) * 64;
    int tid = threadIdx.x;
    int r = tid >> 4, c4 = (tid & 15) * 4;
    #pragma unroll
    for (int p = 0; p < 4; ++p) {
        int k = kt + p * 16 + r;
        float4 v = *(const float4*)(W + (size_t)k * 1024 + nt + c4);
        tile[c4 + 0][p * 16 + r] = v.x;
        tile[c4 + 1][p * 16 + r] = v.y;
        tile[c4 + 2][p * 16 + r] = v.z;
        tile[c4 + 3][p * 16 + r] = v.w;
    }
    __syncthreads();
    #pragma unroll
    for (int p = 0; p < 4; ++p) {
        int nl = p * 16 + r;
        ushort4 o;
        o.x = f2b(tile[nl][c4 + 0]); o.y = f2b(tile[nl][c4 + 1]);
        o.z = f2b(tile[nl][c4 + 2]); o.w = f2b(tile[nl][c4 + 3]);
        *(ushort4*)(Wt + (size_t)(nt + nl) * 1024 + kt + c4) = o;
    }
}

// Wut[b][n][k] = bf16(Wu[k][n] * p_av[b][k])  (fold p_av into per-batch B)
__global__ __launch_bounds__(256) void wu_prime(const float* __restrict__ Wu,
                                                const float* __restrict__ p_av,
                                                u16* __restrict__ Wut) {
    __shared__ float tile[64][65];
    int kt = (blockIdx.x & 15) * 64;
    int nt = (blockIdx.x >> 4) * 64;
    int tid = threadIdx.x;
    int r = tid >> 4, c4 = (tid & 15) * 4;
    #pragma unroll
    for (int p = 0; p < 4; ++p) {
        int k = kt + p * 16 + r;
        float4 v = *(const float4*)(Wu + (size_t)k * 1024 + nt + c4);
        tile[c4 + 0][p * 16 + r] = v.x;
        tile[c4 + 1][p * 16 + r] = v.y;
        tile[c4 + 2][p * 16 + r] = v.z;
        tile[c4 + 3][p * 16 + r] = v.w;
    }
    __syncthreads();
    for (int b = 0; b < 8; ++b) {
        float4 pv = *(const float4*)(p_av + (size_t)b * 1024 + kt + c4);
        #pragma unroll
        for (int p = 0; p < 4; ++p) {
            int nl = p * 16 + r;
            ushort4 o;
            o.x = f2b(tile[nl][c4 + 0] * pv.x);
            o.y = f2b(tile[nl][c4 + 1] * pv.y);
            o.z = f2b(tile[nl][c4 + 2] * pv.z);
            o.w = f2b(tile[nl][c4 + 3] * pv.w);
            *(ushort4*)(Wut + ((size_t)b * 1024 + nt + nl) * 1024 + kt + c4) = o;
        }
    }
}

__global__ __launch_bounds__(256) void wat_prep(const float* __restrict__ Wa,
                                                u16* __restrict__ Wat) {
    int idx = blockIdx.x * 256 + threadIdx.x;   // 16384 = 16 h * 1024 k
    int h = idx >> 10, k = idx & 1023;
    Wat[idx] = f2b(Wa[(k << 4) + h]);
}

// Wbt[b][h][k] = bf16(Wb[k][h] * q_av[b][k])
__global__ __launch_bounds__(256) void wbt_prep(const float* __restrict__ Wb,
                                                const float* __restrict__ q_av,
                                                u16* __restrict__ Wbt) {
    int idx = blockIdx.x * 256 + threadIdx.x;   // 131072
    int b = idx >> 14, rem = idx & 16383;
    int h = rem >> 10, k = rem & 1023;
    Wbt[idx] = f2b(Wb[(k << 4) + h] * q_av[(b << 10) + k]);
}

__global__ __launch_bounds__(256) void bias_concat(const float* __restrict__ bq,
                                                   const float* __restrict__ bk,
                                                   const float* __restrict__ bv,
                                                   float* __restrict__ outb) {
    int i = blockIdx.x * 256 + threadIdx.x;     // 3072
    outb[i] = (i < 1024) ? bq[i] : (i < 2048 ? bk[i - 1024] : bv[i - 2048]);
}

// ---------------------------------------------------------------- main GEMM
// 128x128 tile, BK=64 (32 MFMA per barrier pair), XOR-swizzled LDS (conflict-
// free ds_read_b128), global_load_lds width=16, XCD-aware block swizzle.
__global__ __launch_bounds__(256)
void gemm_bf16(const u16* __restrict__ A, int lda,
               const u16* __restrict__ Bt,        // [N][K] bf16 (B^T)
               const float* __restrict__ bias,    // [N]
               const u16* __restrict__ addsrc, int ldadd,  // optional epilogue add
               u16* __restrict__ C, int ldc,
               int N, int K, int batch_rows) {    // batch_rows>0: Bt per-batch
    __shared__ u16 As[128 * 64];   // 16 KB, rows of 128 B, XOR-swizzled k-groups
    __shared__ u16 Bs[128 * 64];
    int ntiles = N >> 7;
    int bid = blockIdx.x;
    int mtiles = gridDim.x / ntiles;
    int tm, tn;
    if ((mtiles & 7) == 0) {
        // XCD swizzle: bid&7 ~ XCD; each XCD owns a contiguous band of M-tiles
        int xcd = bid & 7, s = bid >> 3;
        int mper = mtiles >> 3;
        tm = xcd * mper + s / ntiles;
        tn = s - (s / ntiles) * ntiles;
    } else {
        tm = bid / ntiles; tn = bid - (bid / ntiles) * ntiles;
    }
    int m0 = tm << 7, n0 = tn << 7;
    if (batch_rows > 0) Bt += (size_t)(m0 / batch_rows) * (size_t)N * K;
    int tid = threadIdx.x, lane = tid & 63, w = tid >> 6;
    int wm = (w >> 1) << 6, wn = (w & 1) << 6;
    int quad = lane >> 4, l16 = lane & 15;
    int rph = l16 & 7;                 // row phase for XOR swizzle
    int lrow = lane >> 3;              // 0..7: row within 8-row chunk
    int lkg  = (lane & 7) ^ lrow;      // global k-group this lane fetches

    // staging pointers: chunk c = w*4+j covers rows [c*8, c*8+8)
    const u16* pa[4]; const u16* pb[4];
    #pragma unroll
    for (int j = 0; j < 4; ++j) {
        int c = (w << 2) + j;
        int row = (c << 3) + lrow;
        pa[j] = A  + (size_t)(m0 + row) * lda + (lkg << 3);
        pb[j] = Bt + (size_t)(n0 + row) * K   + (lkg << 3);
    }

    f32x4 zero = {0.f, 0.f, 0.f, 0.f};
    f32x4 acc[4][4];
    #pragma unroll
    for (int i = 0; i < 4; ++i)
        #pragma unroll
        for (int j = 0; j < 4; ++j) acc[i][j] = zero;

    for (int kt = 0; kt < K; kt += 64) {
        __syncthreads();
        #pragma unroll
        for (int j = 0; j < 4; ++j) {
            int c = (w << 2) + j;
            GLD16(pa[j], &As[c << 9]);
            GLD16(pb[j], &Bs[c << 9]);
            pa[j] += 64; pb[j] += 64;
        }
        __syncthreads();
        #pragma unroll
        for (int kk = 0; kk < 2; ++kk) {
            bf16x8 a[4], b[4];
            int kg = (((kk << 2) + quad) ^ rph) << 3;  // swizzled k-offset (u16)
            #pragma unroll
            for (int i = 0; i < 4; ++i) {
                a[i] = *(const bf16x8*)&As[((wm + (i << 4) + l16) << 6) + kg];
                b[i] = *(const bf16x8*)&Bs[((wn + (i << 4) + l16) << 6) + kg];
            }
            #pragma unroll
            for (int mi = 0; mi < 4; ++mi)
                #pragma unroll
                for (int ni = 0; ni < 4; ++ni)
                    acc[mi][ni] = __builtin_amdgcn_mfma_f32_16x16x32_bf16(
                        a[mi], b[ni], acc[mi][ni], 0, 0, 0);
        }
    }
    // epilogue: C/D layout col=lane&15, row=quad*4+reg (verified m89/m91)
    #pragma unroll
    for (int mi = 0; mi < 4; ++mi) {
        #pragma unroll
        for (int ni = 0; ni < 4; ++ni) {
            int col = n0 + wn + (ni << 4) + l16;
            float bv = bias[col];
            #pragma unroll
            for (int rg = 0; rg < 4; ++rg) {
                int rowg = m0 + wm + (mi << 4) + (quad << 2) + rg;
                float vv = acc[mi][ni][rg] + bv;
                if (addsrc) vv += b2f(addsrc[(size_t)rowg * ldadd + col]);
                C[(size_t)rowg * ldc + col] = f2b(vv);
            }
        }
    }
}

// ------------------------------------------------- score GEMM ([Nrows]x[16])
// out[b][h][s] = 0.125*(dot(A_row, Bt[h]) + bias16[h]) + mask[b][s]
__global__ __launch_bounds__(256)
void score_gemm(const u16* __restrict__ A, int lda,
                const u16* __restrict__ Bt,     // [16][1024] bf16 (per batch if batched)
                const float* __restrict__ bias16,
                const float* __restrict__ mask, // [8][4096]
                float* __restrict__ outsc,      // [8][16][4096]
                int batched) {
    __shared__ u16 As[64 * 32];
    int m0 = blockIdx.x << 6;
    int tid = threadIdx.x, lane = tid & 63, w = tid >> 6;
    int srow = lane >> 2, scol = (lane & 3) << 3;
    int quad = lane >> 4, l16 = lane & 15;
    const u16* Bb = Bt + (batched ? ((size_t)(m0 >> 12) << 14) : 0);
    f32x4 acc = {0.f, 0.f, 0.f, 0.f};
    for (int kt = 0; kt < 1024; kt += 32) {
        __syncthreads();
        const u16* ga = A + (size_t)(m0 + (w << 4) + srow) * lda + kt + scol;
        GLD16(ga, &As[w << 9]);
        __syncthreads();
        bf16x8 a = *(const bf16x8*)&As[(((w << 4) + l16) << 5) + (quad << 3)];
        bf16x8 b = *(const bf16x8*)&Bb[((size_t)l16 << 10) + kt + (quad << 3)];
        acc = __builtin_amdgcn_mfma_f32_16x16x32_bf16(a, b, acc, 0, 0, 0);
    }
    int bidx = m0 >> 12;
    int sbase = (m0 & 4095) + (w << 4) + (quad << 2);
    float bv = bias16[l16];
    float* orow = outsc + (((size_t)bidx << 4) + l16) * 4096;
    const float* mrow = mask + ((size_t)bidx << 12);
    #pragma unroll
    for (int rg = 0; rg < 4; ++rg)
        orow[sbase + rg] = 0.125f * (acc[rg] + bv) + mrow[sbase + rg];
}

// ------------------------------------- softmax over S + weighted pool per (b,h)
__global__ __launch_bounds__(256)
void pool_kernel(const float* __restrict__ score,   // [8][16][4096]
                 const u16* __restrict__ X, int ldx, // q or k rows, bf16
                 const float* __restrict__ mulvec,   // null or q_av [8][1024]
                 float* __restrict__ outav) {        // [8][1024]
    __shared__ float wbuf[4096];
    __shared__ float red[4];
    __shared__ float psum[16][64];
    int b = blockIdx.x >> 4, h = blockIdx.x & 15;
    int tid = threadIdx.x, lane = tid & 63, w = tid >> 6;
    const float* srow = score + (((size_t)b << 4) + h) * 4096;
    float mx = -1e30f;
    for (int s = tid; s < 4096; s += 256) mx = fmaxf(mx, srow[s]);
    for (int o = 32; o; o >>= 1) mx = fmaxf(mx, __shfl_xor(mx, o));
    if (lane == 0) red[w] = mx;
    __syncthreads();
    mx = fmaxf(fmaxf(red[0], red[1]), fmaxf(red[2], red[3]));
    __syncthreads();
    float sm = 0.f;
    for (int s = tid; s < 4096; s += 256) {
        float e = __expf(srow[s] - mx);
        wbuf[s] = e;
        sm += e;
    }
    for (int o = 32; o; o >>= 1) sm += __shfl_xor(sm, o);
    if (lane == 0) red[w] = sm;
    __syncthreads();
    float inv = 1.f / (red[0] + red[1] + red[2] + red[3]);
    int dg = (tid & 15) << 2;   // 4 of 64 dims in head
    int sc = tid >> 4;          // 16 s-chunks of 256
    const u16* base = X + ((size_t)(b << 12)) * ldx + (h << 6) + dg;
    float a0 = 0, a1 = 0, a2 = 0, a3 = 0;
    for (int s = sc << 8; s < (sc << 8) + 256; ++s) {
        float wv = wbuf[s];
        ushort4 uv = *(const ushort4*)(base + (size_t)s * ldx);
        a0 += wv * b2f(uv.x); a1 += wv * b2f(uv.y);
        a2 += wv * b2f(uv.z); a3 += wv * b2f(uv.w);
    }
    psum[sc][dg + 0] = a0; psum[sc][dg + 1] = a1;
    psum[sc][dg + 2] = a2; psum[sc][dg + 3] = a3;
    __syncthreads();
    if (tid < 64) {
        float t = 0.f;
        #pragma unroll
        for (int j = 0; j < 16; ++j) t += psum[j][tid];
        t *= inv;
        if (mulvec) t *= mulvec[((size_t)b << 10) + (h << 6) + tid];
        outav[((size_t)b << 10) + (h << 6) + tid] = t;
    }
}

// ---------------------------------------------------------------- layernorm
__global__ __launch_bounds__(256)
void ln_kernel(const u16* __restrict__ Z, const float* __restrict__ g,
               const float* __restrict__ bta, float* __restrict__ outp) {
    __shared__ float rs1[4], rs2[4];
    int row = blockIdx.x, tid = threadIdx.x;
    const u16* zr = Z + ((size_t)row << 10);
    ushort4 uv = *(const ushort4*)(zr + (tid << 2));
    float v0 = b2f(uv.x), v1 = b2f(uv.y), v2 = b2f(uv.z), v3 = b2f(uv.w);
    float s = v0 + v1 + v2 + v3;
    float s2 = v0 * v0 + v1 * v1 + v2 * v2 + v3 * v3;
    for (int o = 32; o; o >>= 1) { s += __shfl_xor(s, o); s2 += __shfl_xor(s2, o); }
    if ((tid & 63) == 0) { rs1[tid >> 6] = s; rs2[tid >> 6] = s2; }
    __syncthreads();
    float S = rs1[0] + rs1[1] + rs1[2] + rs1[3];
    float S2 = rs2[0] + rs2[1] + rs2[2] + rs2[3];
    float mean = S * (1.0f / 1024.0f);
    float var = S2 * (1.0f / 1024.0f) - mean * mean;
    float inv = rsqrtf(var + 1e-6f);
    int c = tid << 2;
    float4 o4;
    o4.x = (v0 - mean) * inv * g[c + 0] + bta[c + 0];
    o4.y = (v1 - mean) * inv * g[c + 1] + bta[c + 1];
    o4.z = (v2 - mean) * inv * g[c + 2] + bta[c + 2];
    o4.w = (v3 - mean) * inv * g[c + 3] + bta[c + 3];
    *(float4*)(outp + ((size_t)row << 10) + c) = o4;
}

// ---------------------------------------------------------------- launch

extern "C" void kernel_launch(void* const* d_in, const int* in_sizes, int n_in,
                              void* d_out, int out_size, void* d_ws, size_t ws_size,
                              hipStream_t stream) {
    (void)in_sizes; (void)n_in; (void)out_size;
    const float* x    = (const float*)d_in[0];
    const float* mask = (const float*)d_in[1];
    const float* Wq   = (const float*)d_in[2];
    const float* bq   = (const float*)d_in[3];
    const float* Wk   = (const float*)d_in[4];
    const float* bk   = (const float*)d_in[5];
    const float* Wv   = (const float*)d_in[6];
    const float* bv   = (const float*)d_in[7];
    const float* Wa   = (const float*)d_in[8];
    const float* ba   = (const float*)d_in[9];
    const float* Wb   = (const float*)d_in[10];
    const float* bb   = (const float*)d_in[11];
    const float* Wu   = (const float*)d_in[12];
    const float* bu   = (const float*)d_in[13];
    const float* Wo   = (const float*)d_in[14];
    const float* bo   = (const float*)d_in[15];
    const float* ln_g = (const float*)d_in[16];
    const float* ln_b = (const float*)d_in[17];
    float* outp = (float*)d_out;

    char* ws = (char*)d_ws;
    // layout (bytes, all 256-aligned)
    u16*   xb    = (u16*)(ws);                     //  67,108,864  x bf16; later aliased by z
    u16*   qkv   = (u16*)(ws + 67108864);          // 201,326,592  [32768][3072]; q-region aliased by t
    u16*   Wqkvt = (u16*)(ws + 268435456);         //   6,291,456
    u16*   Wot   = (u16*)(ws + 274726912);         //   2,097,152
    u16*   Wat   = (u16*)(ws + 276824064);         //      32,768
    u16*   Wbt   = (u16*)(ws + 276856832);         //     262,144
    float* score = (float*)(ws + 277118976);       //   2,097,152 (reused for a & b scores)
    float* q_av  = (float*)(ws + 279216128);       //      32,768
    float* p_av  = (float*)(ws + 279248896);       //      32,768
    float* biasq = (float*)(ws + 279281664);       //      12,288
    u16*   Wubt  = (u16*)(ws + 279293952);         //  16,777,216  -> total 296,071,168
    if (ws_size < 296071168ULL) return;

    convert_x<<<16384, 256, 0, stream>>>(x, xb);
    transpose_w<<<256, 256, 0, stream>>>(Wq, Wqkvt);
    transpose_w<<<256, 256, 0, stream>>>(Wk, Wqkvt + 1048576);
    transpose_w<<<256, 256, 0, stream>>>(Wv, Wqkvt + 2097152);
    transpose_w<<<256, 256, 0, stream>>>(Wo, Wot);
    wat_prep<<<64, 256, 0, stream>>>(Wa, Wat);
    bias_concat<<<12, 256, 0, stream>>>(bq, bk, bv, biasq);

    // qkv = x @ [Wq|Wk|Wv] + bias   (M=32768, N=3072, K=1024)
    gemm_bf16<<<6144, 256, 0, stream>>>(xb, 1024, Wqkvt, biasq,
                                        nullptr, 0, qkv, 3072, 3072, 1024, 0);
    // ascore
    score_gemm<<<512, 256, 0, stream>>>(qkv, 3072, Wat, ba, mask, score, 0);
    // alpha softmax+pool -> q_av
    pool_kernel<<<128, 256, 0, stream>>>(score, qkv, 3072, nullptr, q_av);
    // per-batch Wb' = diag(q_av) Wb
    wbt_prep<<<512, 256, 0, stream>>>(Wb, q_av, Wbt);
    // bscore = k @ Wb'
    score_gemm<<<512, 256, 0, stream>>>(qkv + 1024, 3072, Wbt, bb, mask, score, 1);
    // beta softmax+pool, times q_av -> p_av
    pool_kernel<<<128, 256, 0, stream>>>(score, qkv + 1024, 3072, q_av, p_av);
    // per-batch Wu' = diag(p_av) Wu (transposed, bf16)
    wu_prime<<<256, 256, 0, stream>>>(Wu, p_av, Wubt);
    // t = v @ Wu'_b + bu + q   (writes over q region; element read-before-write)
    gemm_bf16<<<2048, 256, 0, stream>>>(qkv + 2048, 3072, Wubt, bu,
                                        qkv, 3072, qkv, 3072, 1024, 1024, 4096);
    // z = t @ Wo^T + bo + x    (writes over xb; element read-before-write)
    gemm_bf16<<<2048, 256, 0, stream>>>(qkv, 3072, Wot, bo,
                                        xb, 1024, xb, 1024, 1024, 1024, 0);
    // layernorm -> out (f32)
    ln_kernel<<<32768, 256, 0, stream>>>(xb, ln_g, ln_b, outp);
}

// Round 3
// 884.608 us; speedup vs baseline: 1.1547x; 1.0578x over previous
//
#include <hip/hip_runtime.h>

typedef unsigned short u16;
typedef __bf16 bf16x8 __attribute__((ext_vector_type(8)));
typedef float  f32x4  __attribute__((ext_vector_type(4)));

__device__ __forceinline__ float b2f(u16 u) {
    unsigned int v = ((unsigned int)u) << 16;
    return __builtin_bit_cast(float, v);
}
__device__ __forceinline__ u16 f2b(float f) {
    unsigned int v = __builtin_bit_cast(unsigned int, f);
    v += 0x7fffu + ((v >> 16) & 1u);
    return (u16)(v >> 16);
}

// async global->LDS, 16B per lane; LDS dest = wave-uniform base + lane*16
#define GLD16(gp, lp) __builtin_amdgcn_global_load_lds( \
    (const __attribute__((address_space(1))) void*)(gp), \
    (__attribute__((address_space(3))) void*)(lp), 16, 0, 0)

// ---------------------------------------------------------------- prep kernels

__global__ __launch_bounds__(256) void convert_x(const float* __restrict__ x,
                                                 u16* __restrict__ xb) {
    size_t i = ((size_t)blockIdx.x * 256 + threadIdx.x) * 8;
    float4 v0 = *(const float4*)(x + i);
    float4 v1 = *(const float4*)(x + i + 4);
    ushort4 o0, o1;
    o0.x = f2b(v0.x); o0.y = f2b(v0.y); o0.z = f2b(v0.z); o0.w = f2b(v0.w);
    o1.x = f2b(v1.x); o1.y = f2b(v1.y); o1.z = f2b(v1.z); o1.w = f2b(v1.w);
    *(ushort4*)(xb + i)     = o0;
    *(ushort4*)(xb + i + 4) = o1;
}

// Wt[n][k] = bf16(W[k][n]), 1024x1024, LDS-tiled transpose
__global__ __launch_bounds__(256) void transpose_w(const float* __restrict__ W,
                                                   u16* __restrict__ Wt) {
    __shared__ float tile[64][65];
    int kt = (blockIdx.x & 15) * 64;
    int nt = (blockIdx.x >> 4) * 64;
    int tid = threadIdx.x;
    int r = tid >> 4, c4 = (tid & 15) * 4;
    #pragma unroll
    for (int p = 0; p < 4; ++p) {
        int k = kt + p * 16 + r;
        float4 v = *(const float4*)(W + (size_t)k * 1024 + nt + c4);
        tile[c4 + 0][p * 16 + r] = v.x;
        tile[c4 + 1][p * 16 + r] = v.y;
        tile[c4 + 2][p * 16 + r] = v.z;
        tile[c4 + 3][p * 16 + r] = v.w;
    }
    __syncthreads();
    #pragma unroll
    for (int p = 0; p < 4; ++p) {
        int nl = p * 16 + r;
        ushort4 o;
        o.x = f2b(tile[nl][c4 + 0]); o.y = f2b(tile[nl][c4 + 1]);
        o.z = f2b(tile[nl][c4 + 2]); o.w = f2b(tile[nl][c4 + 3]);
        *(ushort4*)(Wt + (size_t)(nt + nl) * 1024 + kt + c4) = o;
    }
}

// Wut[b][n][k] = bf16(Wu[k][n] * p_av[b][k])  (fold p_av into per-batch B)
__global__ __launch_bounds__(256) void wu_prime(const float* __restrict__ Wu,
                                                const float* __restrict__ p_av,
                                                u16* __restrict__ Wut) {
    __shared__ float tile[64][65];
    int kt = (blockIdx.x & 15) * 64;
    int nt = (blockIdx.x >> 4) * 64;
    int tid = threadIdx.x;
    int r = tid >> 4, c4 = (tid & 15) * 4;
    #pragma unroll
    for (int p = 0; p < 4; ++p) {
        int k = kt + p * 16 + r;
        float4 v = *(const float4*)(Wu + (size_t)k * 1024 + nt + c4);
        tile[c4 + 0][p * 16 + r] = v.x;
        tile[c4 + 1][p * 16 + r] = v.y;
        tile[c4 + 2][p * 16 + r] = v.z;
        tile[c4 + 3][p * 16 + r] = v.w;
    }
    __syncthreads();
    for (int b = 0; b < 8; ++b) {
        float4 pv = *(const float4*)(p_av + (size_t)b * 1024 + kt + c4);
        #pragma unroll
        for (int p = 0; p < 4; ++p) {
            int nl = p * 16 + r;
            ushort4 o;
            o.x = f2b(tile[nl][c4 + 0] * pv.x);
            o.y = f2b(tile[nl][c4 + 1] * pv.y);
            o.z = f2b(tile[nl][c4 + 2] * pv.z);
            o.w = f2b(tile[nl][c4 + 3] * pv.w);
            *(ushort4*)(Wut + ((size_t)b * 1024 + nt + nl) * 1024 + kt + c4) = o;
        }
    }
}

__global__ __launch_bounds__(256) void wat_prep(const float* __restrict__ Wa,
                                                u16* __restrict__ Wat) {
    int idx = blockIdx.x * 256 + threadIdx.x;   // 16384 = 16 h * 1024 k
    int h = idx >> 10, k = idx & 1023;
    Wat[idx] = f2b(Wa[(k << 4) + h]);
}

// Wbt[b][h][k] = bf16(Wb[k][h] * q_av[b][k])
__global__ __launch_bounds__(256) void wbt_prep(const float* __restrict__ Wb,
                                                const float* __restrict__ q_av,
                                                u16* __restrict__ Wbt) {
    int idx = blockIdx.x * 256 + threadIdx.x;   // 131072
    int b = idx >> 14, rem = idx & 16383;
    int h = rem >> 10, k = rem & 1023;
    Wbt[idx] = f2b(Wb[(k << 4) + h] * q_av[(b << 10) + k]);
}

__global__ __launch_bounds__(256) void bias_concat(const float* __restrict__ bq,
                                                   const float* __restrict__ bk,
                                                   const float* __restrict__ bv,
                                                   float* __restrict__ outb) {
    int i = blockIdx.x * 256 + threadIdx.x;     // 3072
    outb[i] = (i < 1024) ? bq[i] : (i < 2048 ? bk[i - 1024] : bv[i - 2048]);
}

// ---------------------------------------------------------------- main GEMM
// 128x128 tile, BK=64, XOR-swizzled LDS (0 bank conflicts, verified R2),
// global_load_lds width=16, XCD-aware block swizzle.
// Register diet: 2 per-lane i32 indices + SGPR strides; __launch_bounds__(256,4)
// targets 128 regs/wave (64 AGPR acc + ~60 VGPR) -> 4 blocks/CU.
__global__ __launch_bounds__(256, 4)
void gemm_bf16(const u16* __restrict__ A, int lda,
               const u16* __restrict__ Bt,        // [N][K] bf16 (B^T)
               const float* __restrict__ bias,    // [N]
               const u16* __restrict__ addsrc, int ldadd,  // optional epilogue add
               u16* __restrict__ C, int ldc,
               int N, int K, int batch_rows) {    // batch_rows>0: Bt per-batch
    __shared__ u16 As[128 * 64];   // 16 KB, rows of 128 B, XOR-swizzled k-groups
    __shared__ u16 Bs[128 * 64];
    int ntiles = N >> 7;
    int bid = blockIdx.x;
    int mtiles = gridDim.x / ntiles;
    int tm, tn;
    if ((mtiles & 7) == 0) {
        int xcd = bid & 7, s = bid >> 3;
        int mper = mtiles >> 3;
        tm = xcd * mper + s / ntiles;
        tn = s - (s / ntiles) * ntiles;
    } else {
        tm = bid / ntiles; tn = bid - (bid / ntiles) * ntiles;
    }
    int m0 = tm << 7, n0 = tn << 7;
    if (batch_rows > 0) Bt += (size_t)(m0 / batch_rows) * (size_t)N * K;
    int tid = threadIdx.x, lane = tid & 63, w = tid >> 6;
    int wm = (w >> 1) << 6, wn = (w & 1) << 6;
    int quad = lane >> 4, l16 = lane & 15;
    int rph = l16 & 7;                 // row phase for XOR swizzle
    int lrow = lane >> 3;              // 0..7: row within 8-row chunk
    int lkg  = (lane & 7) ^ lrow;      // global k-group this lane fetches

    // per-lane 32-bit element indices; j/kt offsets are wave-uniform (SGPR)
    int idxA = (m0 + (w << 5) + lrow) * lda + (lkg << 3);
    int idxB = (n0 + (w << 5) + lrow) * K   + (lkg << 3);
    int stepA = lda << 3, stepB = K << 3;   // 8 rows of elements

    f32x4 zero = {0.f, 0.f, 0.f, 0.f};
    f32x4 acc[4][4];
    #pragma unroll
    for (int i = 0; i < 4; ++i)
        #pragma unroll
        for (int j = 0; j < 4; ++j) acc[i][j] = zero;

    for (int kt = 0; kt < K; kt += 64) {
        __syncthreads();
        #pragma unroll
        for (int j = 0; j < 4; ++j) {
            int c = (w << 2) + j;
            GLD16(A  + (idxA + j * stepA + kt), &As[c << 9]);
            GLD16(Bt + (idxB + j * stepB + kt), &Bs[c << 9]);
        }
        __syncthreads();
        #pragma unroll
        for (int kk = 0; kk < 2; ++kk) {
            bf16x8 a[4], b[4];
            int kg = (((kk << 2) + quad) ^ rph) << 3;  // swizzled k-offset (u16)
            #pragma unroll
            for (int i = 0; i < 4; ++i) {
                a[i] = *(const bf16x8*)&As[((wm + (i << 4) + l16) << 6) + kg];
                b[i] = *(const bf16x8*)&Bs[((wn + (i << 4) + l16) << 6) + kg];
            }
            #pragma unroll
            for (int mi = 0; mi < 4; ++mi)
                #pragma unroll
                for (int ni = 0; ni < 4; ++ni)
                    acc[mi][ni] = __builtin_amdgcn_mfma_f32_16x16x32_bf16(
                        a[mi], b[ni], acc[mi][ni], 0, 0, 0);
        }
    }
    // epilogue: C/D layout col=lane&15, row=quad*4+reg (verified m89/m91)
    #pragma unroll
    for (int mi = 0; mi < 4; ++mi) {
        #pragma unroll
        for (int ni = 0; ni < 4; ++ni) {
            int col = n0 + wn + (ni << 4) + l16;
            float bv = bias[col];
            #pragma unroll
            for (int rg = 0; rg < 4; ++rg) {
                int rowg = m0 + wm + (mi << 4) + (quad << 2) + rg;
                float vv = acc[mi][ni][rg] + bv;
                if (addsrc) vv += b2f(addsrc[(size_t)rowg * ldadd + col]);
                C[(size_t)rowg * ldc + col] = f2b(vv);
            }
        }
    }
}

// ------------------------------------------------- score GEMM ([Nrows]x[16])
// out[b][h][s] = 0.125*(dot(A_row, Bt[h]) + bias16[h]) + mask[b][s]
// 256 rows/block, BK=64, 8 MFMA per barrier pair, XOR-swizzled LDS.
__global__ __launch_bounds__(256)
void score_gemm(const u16* __restrict__ A, int lda,
                const u16* __restrict__ Bt,     // [16][1024] bf16 (per batch if batched)
                const float* __restrict__ bias16,
                const float* __restrict__ mask, // [8][4096]
                float* __restrict__ outsc,      // [8][16][4096]
                int batched) {
    __shared__ u16 As[256 * 64];   // 32 KB
    __shared__ u16 Bs[16 * 64];    //  2 KB
    int m0 = blockIdx.x << 8;      // 256 rows per block (within one batch: 4096%256==0)
    int tid = threadIdx.x, lane = tid & 63, w = tid >> 6;
    int quad = lane >> 4, l16 = lane & 15;
    int rph = l16 & 7;
    int lrow = lane >> 3;
    int lkg  = (lane & 7) ^ lrow;
    const u16* Bb = Bt + (batched ? ((size_t)(m0 >> 12) << 14) : 0);

    int idxA = (m0 + (w << 6) + lrow) * lda + (lkg << 3);  // chunk c=w*8+j rows
    int stepA = lda << 3;
    int idxB = lrow * 1024 + (lkg << 3);                    // rows h = c*8+lrow

    f32x4 acc4[4];
    #pragma unroll
    for (int i = 0; i < 4; ++i) acc4[i] = (f32x4){0.f, 0.f, 0.f, 0.f};

    for (int kt = 0; kt < 1024; kt += 64) {
        __syncthreads();
        #pragma unroll
        for (int j = 0; j < 8; ++j) {
            int c = (w << 3) + j;
            GLD16(A + (idxA + j * stepA + kt), &As[c << 9]);
        }
        if (w < 2)
            GLD16(Bb + (idxB + w * 8192 + kt), &Bs[w << 9]);
        __syncthreads();
        #pragma unroll
        for (int kk = 0; kk < 2; ++kk) {
            int kg = (((kk << 2) + quad) ^ rph) << 3;
            bf16x8 b = *(const bf16x8*)&Bs[(l16 << 6) + kg];
            #pragma unroll
            for (int mi = 0; mi < 4; ++mi) {
                bf16x8 a = *(const bf16x8*)&As[(((w << 6) + (mi << 4) + l16) << 6) + kg];
                acc4[mi] = __builtin_amdgcn_mfma_f32_16x16x32_bf16(a, b, acc4[mi], 0, 0, 0);
            }
        }
    }
    int bidx = m0 >> 12;
    float bv = bias16[l16];
    float* orow = outsc + (((size_t)bidx << 4) + l16) * 4096;
    const float* mrow = mask + ((size_t)bidx << 12);
    #pragma unroll
    for (int mi = 0; mi < 4; ++mi) {
        int sbase = (m0 & 4095) + (w << 6) + (mi << 4) + (quad << 2);
        #pragma unroll
        for (int rg = 0; rg < 4; ++rg)
            orow[sbase + rg] = 0.125f * (acc4[mi][rg] + bv) + mrow[sbase + rg];
    }
}

// ------------------------------------- softmax over S + weighted pool per (b,h)
__global__ __launch_bounds__(256)
void pool_kernel(const float* __restrict__ score,   // [8][16][4096]
                 const u16* __restrict__ X, int ldx, // q or k rows, bf16
                 const float* __restrict__ mulvec,   // null or q_av [8][1024]
                 float* __restrict__ outav) {        // [8][1024]
    __shared__ float wbuf[4096];
    __shared__ float red[4];
    __shared__ float psum[16][64];
    int b = blockIdx.x >> 4, h = blockIdx.x & 15;
    int tid = threadIdx.x, lane = tid & 63, w = tid >> 6;
    const float* srow = score + (((size_t)b << 4) + h) * 4096;
    float mx = -1e30f;
    for (int s = tid; s < 4096; s += 256) mx = fmaxf(mx, srow[s]);
    for (int o = 32; o; o >>= 1) mx = fmaxf(mx, __shfl_xor(mx, o));
    if (lane == 0) red[w] = mx;
    __syncthreads();
    mx = fmaxf(fmaxf(red[0], red[1]), fmaxf(red[2], red[3]));
    __syncthreads();
    float sm = 0.f;
    for (int s = tid; s < 4096; s += 256) {
        float e = __expf(srow[s] - mx);
        wbuf[s] = e;
        sm += e;
    }
    for (int o = 32; o; o >>= 1) sm += __shfl_xor(sm, o);
    if (lane == 0) red[w] = sm;
    __syncthreads();
    float inv = 1.f / (red[0] + red[1] + red[2] + red[3]);
    int dg = (tid & 15) << 2;   // 4 of 64 dims in head
    int sc = tid >> 4;          // 16 s-chunks of 256
    const u16* base = X + ((size_t)(b << 12)) * ldx + (h << 6) + dg;
    float a0 = 0, a1 = 0, a2 = 0, a3 = 0;
    for (int s = sc << 8; s < (sc << 8) + 256; ++s) {
        float wv = wbuf[s];
        ushort4 uv = *(const ushort4*)(base + (size_t)s * ldx);
        a0 += wv * b2f(uv.x); a1 += wv * b2f(uv.y);
        a2 += wv * b2f(uv.z); a3 += wv * b2f(uv.w);
    }
    psum[sc][dg + 0] = a0; psum[sc][dg + 1] = a1;
    psum[sc][dg + 2] = a2; psum[sc][dg + 3] = a3;
    __syncthreads();
    if (tid < 64) {
        float t = 0.f;
        #pragma unroll
        for (int j = 0; j < 16; ++j) t += psum[j][tid];
        t *= inv;
        if (mulvec) t *= mulvec[((size_t)b << 10) + (h << 6) + tid];
        outav[((size_t)b << 10) + (h << 6) + tid] = t;
    }
}

// ---------------------------------------------------------------- layernorm
__global__ __launch_bounds__(256)
void ln_kernel(const u16* __restrict__ Z, const float* __restrict__ g,
               const float* __restrict__ bta, float* __restrict__ outp) {
    __shared__ float rs1[4], rs2[4];
    int row = blockIdx.x, tid = threadIdx.x;
    const u16* zr = Z + ((size_t)row << 10);
    ushort4 uv = *(const ushort4*)(zr + (tid << 2));
    float v0 = b2f(uv.x), v1 = b2f(uv.y), v2 = b2f(uv.z), v3 = b2f(uv.w);
    float s = v0 + v1 + v2 + v3;
    float s2 = v0 * v0 + v1 * v1 + v2 * v2 + v3 * v3;
    for (int o = 32; o; o >>= 1) { s += __shfl_xor(s, o); s2 += __shfl_xor(s2, o); }
    if ((tid & 63) == 0) { rs1[tid >> 6] = s; rs2[tid >> 6] = s2; }
    __syncthreads();
    float S = rs1[0] + rs1[1] + rs1[2] + rs1[3];
    float S2 = rs2[0] + rs2[1] + rs2[2] + rs2[3];
    float mean = S * (1.0f / 1024.0f);
    float var = S2 * (1.0f / 1024.0f) - mean * mean;
    float inv = rsqrtf(var + 1e-6f);
    int c = tid << 2;
    float4 o4;
    o4.x = (v0 - mean) * inv * g[c + 0] + bta[c + 0];
    o4.y = (v1 - mean) * inv * g[c + 1] + bta[c + 1];
    o4.z = (v2 - mean) * inv * g[c + 2] + bta[c + 2];
    o4.w = (v3 - mean) * inv * g[c + 3] + bta[c + 3];
    *(float4*)(outp + ((size_t)row << 10) + c) = o4;
}

// ---------------------------------------------------------------- launch

extern "C" void kernel_launch(void* const* d_in, const int* in_sizes, int n_in,
                              void* d_out, int out_size, void* d_ws, size_t ws_size,
                              hipStream_t stream) {
    (void)in_sizes; (void)n_in; (void)out_size;
    const float* x    = (const float*)d_in[0];
    const float* mask = (const float*)d_in[1];
    const float* Wq   = (const float*)d_in[2];
    const float* bq   = (const float*)d_in[3];
    const float* Wk   = (const float*)d_in[4];
    const float* bk   = (const float*)d_in[5];
    const float* Wv   = (const float*)d_in[6];
    const float* bv   = (const float*)d_in[7];
    const float* Wa   = (const float*)d_in[8];
    const float* ba   = (const float*)d_in[9];
    const float* Wb   = (const float*)d_in[10];
    const float* bb   = (const float*)d_in[11];
    const float* Wu   = (const float*)d_in[12];
    const float* bu   = (const float*)d_in[13];
    const float* Wo   = (const float*)d_in[14];
    const float* bo   = (const float*)d_in[15];
    const float* ln_g = (const float*)d_in[16];
    const float* ln_b = (const float*)d_in[17];
    float* outp = (float*)d_out;

    char* ws = (char*)d_ws;
    // layout (bytes, all 256-aligned)
    u16*   xb    = (u16*)(ws);                     //  67,108,864  x bf16; later aliased by z
    u16*   qkv   = (u16*)(ws + 67108864);          // 201,326,592  [32768][3072]; q-region aliased by t
    u16*   Wqkvt = (u16*)(ws + 268435456);         //   6,291,456
    u16*   Wot   = (u16*)(ws + 274726912);         //   2,097,152
    u16*   Wat   = (u16*)(ws + 276824064);         //      32,768
    u16*   Wbt   = (u16*)(ws + 276856832);         //     262,144
    float* score = (float*)(ws + 277118976);       //   2,097,152 (reused for a & b scores)
    float* q_av  = (float*)(ws + 279216128);       //      32,768
    float* p_av  = (float*)(ws + 279248896);       //      32,768
    float* biasq = (float*)(ws + 279281664);       //      12,288
    u16*   Wubt  = (u16*)(ws + 279293952);         //  16,777,216  -> total 296,071,168
    if (ws_size < 296071168ULL) return;

    convert_x<<<16384, 256, 0, stream>>>(x, xb);
    transpose_w<<<256, 256, 0, stream>>>(Wq, Wqkvt);
    transpose_w<<<256, 256, 0, stream>>>(Wk, Wqkvt + 1048576);
    transpose_w<<<256, 256, 0, stream>>>(Wv, Wqkvt + 2097152);
    transpose_w<<<256, 256, 0, stream>>>(Wo, Wot);
    wat_prep<<<64, 256, 0, stream>>>(Wa, Wat);
    bias_concat<<<12, 256, 0, stream>>>(bq, bk, bv, biasq);

    // qkv = x @ [Wq|Wk|Wv] + bias   (M=32768, N=3072, K=1024)
    gemm_bf16<<<6144, 256, 0, stream>>>(xb, 1024, Wqkvt, biasq,
                                        nullptr, 0, qkv, 3072, 3072, 1024, 0);
    // ascore
    score_gemm<<<128, 256, 0, stream>>>(qkv, 3072, Wat, ba, mask, score, 0);
    // alpha softmax+pool -> q_av
    pool_kernel<<<128, 256, 0, stream>>>(score, qkv, 3072, nullptr, q_av);
    // per-batch Wb' = diag(q_av) Wb
    wbt_prep<<<512, 256, 0, stream>>>(Wb, q_av, Wbt);
    // bscore = k @ Wb'
    score_gemm<<<128, 256, 0, stream>>>(qkv + 1024, 3072, Wbt, bb, mask, score, 1);
    // beta softmax+pool, times q_av -> p_av
    pool_kernel<<<128, 256, 0, stream>>>(score, qkv + 1024, 3072, q_av, p_av);
    // per-batch Wu' = diag(p_av) Wu (transposed, bf16)
    wu_prime<<<256, 256, 0, stream>>>(Wu, p_av, Wubt);
    // t = v @ Wu'_b + bu + q   (writes over q region; element read-before-write)
    gemm_bf16<<<2048, 256, 0, stream>>>(qkv + 2048, 3072, Wubt, bu,
                                        qkv, 3072, qkv, 3072, 1024, 1024, 4096);
    // z = t @ Wo^T + bo + x    (writes over xb; element read-before-write)
    gemm_bf16<<<2048, 256, 0, stream>>>(qkv, 3072, Wot, bo,
                                        xb, 1024, xb, 1024, 1024, 1024, 0);
    // layernorm -> out (f32)
    ln_kernel<<<32768, 256, 0, stream>>>(xb, ln_g, ln_b, outp);
}